// Round 9
// baseline (101.121 us; speedup 1.0000x reference)
//
#include <hip/hip_runtime.h>

// Problem shape (fixed by reference): N=64, C=1024, H=W=28 -> HW=784
#define HWD 784
#define Q4  196            // HWD/4 float4 slots per channel row
#define CD  1024
#define ND  64

#define CHPB 32            // channels per pass1 block (4 waves x 8)
#define NCHUNK (CD / CHPB) // 32 partial chunks

typedef float f32x4 __attribute__((ext_vector_type(4)));

__device__ __forceinline__ float4 cam4(float4 v, float wc) {
    float4 r;
    r.x = fmaxf(v.x * wc, 0.f);
    r.y = fmaxf(v.y * wc, 0.f);
    r.z = fmaxf(v.z * wc, 0.f);
    r.w = fmaxf(v.w * wc, 0.f);
    return r;
}
__device__ __forceinline__ float max4(float4 v) {
    return fmaxf(fmaxf(v.x, v.y), fmaxf(v.z, v.w));
}
__device__ __forceinline__ void accdrop(float4& a, float4 c, float thr) {
    a.x += (c.x > thr) ? 0.f : c.x;
    a.y += (c.y > thr) ? 0.f : c.y;
    a.z += (c.z > thr) ? 0.f : c.z;
    a.w += (c.w > thr) ? 0.f : c.w;
}

// ---------------------------------------------------------------------------
// Pass 1: block = (chunk of 32 channels, n), 256 threads = 4 waves.
// Each wave: 8 consecutive channels in 2 phases of 4. Per phase: 16 float4
// loads in flight, 4 INDEPENDENT shfl-butterfly chains (ILP-4 on the serial
// cross-lane max), dropped values accumulated in registers (position-
// aligned across channels). One LDS write/wave, one barrier, 4-way sum,
// coalesced Spart store. No atomics. Grid 2048 blocks -> good tail overlap.
// ---------------------------------------------------------------------------
__global__ void __launch_bounds__(256) pass1_kernel(const float* __restrict__ x,
                                                    const float* __restrict__ w,
                                                    const float* __restrict__ mu_p,
                                                    float* __restrict__ Spart) {
    __shared__ float4 drp[4][197];   // wave stride 197*4 = 788 floats

    const int t = threadIdx.x;
    const int wave = t >> 6;
    const int lane = t & 63;
    const int n = blockIdx.y;
    const int cbase = blockIdx.x * CHPB + wave * 8;
    const float mu = mu_p[0];

    const float4* rows = reinterpret_cast<const float4*>(x + ((size_t)n * CD + cbase) * HWD);

    float4 acc0 = {0.f,0.f,0.f,0.f}, acc1 = {0.f,0.f,0.f,0.f};
    float4 acc2 = {0.f,0.f,0.f,0.f}, acc3 = {0.f,0.f,0.f,0.f};

    #pragma unroll
    for (int ph = 0; ph < 2; ++ph) {
        const float4* r0 = rows + (ph * 4) * Q4;
        const float4* r1 = r0 + Q4;
        const float4* r2 = r1 + Q4;
        const float4* r3 = r2 + Q4;
        // 16 loads in flight (12 full + 4 masked tail)
        float4 a0 = r0[lane], a1 = r0[lane + 64], a2 = r0[lane + 128];
        float4 b0 = r1[lane], b1 = r1[lane + 64], b2 = r1[lane + 128];
        float4 c0 = r2[lane], c1 = r2[lane + 64], c2 = r2[lane + 128];
        float4 d0 = r3[lane], d1 = r3[lane + 64], d2 = r3[lane + 128];
        float4 a3 = {0.f,0.f,0.f,0.f}, b3 = {0.f,0.f,0.f,0.f};
        float4 c3 = {0.f,0.f,0.f,0.f}, d3 = {0.f,0.f,0.f,0.f};
        if (lane < 4) {
            a3 = r0[192 + lane]; b3 = r1[192 + lane];
            c3 = r2[192 + lane]; d3 = r3[192 + lane];
        }

        const float w0 = w[cbase + ph * 4 + 0];
        const float w1 = w[cbase + ph * 4 + 1];
        const float w2 = w[cbase + ph * 4 + 2];
        const float w3 = w[cbase + ph * 4 + 3];

        a0 = cam4(a0, w0); a1 = cam4(a1, w0); a2 = cam4(a2, w0); a3 = cam4(a3, w0);
        b0 = cam4(b0, w1); b1 = cam4(b1, w1); b2 = cam4(b2, w1); b3 = cam4(b3, w1);
        c0 = cam4(c0, w2); c1 = cam4(c1, w2); c2 = cam4(c2, w2); c3 = cam4(c3, w2);
        d0 = cam4(d0, w3); d1 = cam4(d1, w3); d2 = cam4(d2, w3); d3 = cam4(d3, w3);

        float m0 = fmaxf(fmaxf(max4(a0), max4(a1)), fmaxf(max4(a2), max4(a3)));
        float m1 = fmaxf(fmaxf(max4(b0), max4(b1)), fmaxf(max4(b2), max4(b3)));
        float m2 = fmaxf(fmaxf(max4(c0), max4(c1)), fmaxf(max4(c2), max4(c3)));
        float m3 = fmaxf(fmaxf(max4(d0), max4(d1)), fmaxf(max4(d2), max4(d3)));

        // 4 independent butterfly chains
        #pragma unroll
        for (int off = 32; off > 0; off >>= 1) {
            m0 = fmaxf(m0, __shfl_xor(m0, off, 64));
            m1 = fmaxf(m1, __shfl_xor(m1, off, 64));
            m2 = fmaxf(m2, __shfl_xor(m2, off, 64));
            m3 = fmaxf(m3, __shfl_xor(m3, off, 64));
        }
        const float t0 = m0 * mu, t1 = m1 * mu, t2 = m2 * mu, t3 = m3 * mu;

        accdrop(acc0, a0, t0); accdrop(acc1, a1, t0); accdrop(acc2, a2, t0); accdrop(acc3, a3, t0);
        accdrop(acc0, b0, t1); accdrop(acc1, b1, t1); accdrop(acc2, b2, t1); accdrop(acc3, b3, t1);
        accdrop(acc0, c0, t2); accdrop(acc1, c1, t2); accdrop(acc2, c2, t2); accdrop(acc3, c3, t2);
        accdrop(acc0, d0, t3); accdrop(acc1, d1, t3); accdrop(acc2, d2, t3); accdrop(acc3, d3, t3);
    }

    drp[wave][lane]       = acc0;
    drp[wave][64 + lane]  = acc1;
    drp[wave][128 + lane] = acc2;
    if (lane < 4) drp[wave][192 + lane] = acc3;
    __syncthreads();

    const float* f = reinterpret_cast<const float*>(&drp[0][0]);
    float* sp = Spart + ((size_t)blockIdx.x * ND + n) * HWD;
    for (int p = t; p < HWD; p += 256)
        sp[p] = f[p] + f[788 + p] + f[2 * 788 + p] + f[3 * 788 + p];
}

// ---------------------------------------------------------------------------
// Reduce: S[n,p] = sum over 32 chunks of Spart[chunk][n][p]. Coalesced.
// ---------------------------------------------------------------------------
__global__ void __launch_bounds__(256) reduce_kernel(const float* __restrict__ Spart,
                                                     float* __restrict__ S) {
    const int j = blockIdx.x * 256 + threadIdx.x;   // 0 .. 50175
    float s = 0.f;
    #pragma unroll
    for (int ch = 0; ch < NCHUNK; ++ch)
        s += Spart[(size_t)ch * ND * HWD + j];
    S[j] = s;
}

// ---------------------------------------------------------------------------
// Mult: pure streaming out = x * S (x read is L3-hot after pass1; NT store
// keeps the out stream from evicting x). ~45us measured.
// ---------------------------------------------------------------------------
__global__ void __launch_bounds__(256) mult_kernel(const float* __restrict__ x,
                                                   const float* __restrict__ S,
                                                   float* __restrict__ out) {
    const float4* x4 = reinterpret_cast<const float4*>(x);
    const float4* S4 = reinterpret_cast<const float4*>(S);

    int i4 = blockIdx.x * 256 + threadIdx.x;
    #pragma unroll 4
    for (int it = 0; it < 16; ++it, i4 += 3136 * 256) {
        const int r = i4 / Q4;                  // nc index (magic-mul)
        const int p4 = i4 - r * Q4;
        const int n = r >> 10;
        float4 xv = x4[i4];
        float4 sv = S4[n * Q4 + p4];
        float4 o;
        o.x = xv.x * sv.x;
        o.y = xv.y * sv.y;
        o.z = xv.z * sv.z;
        o.w = xv.w * sv.w;
        __builtin_nontemporal_store(*reinterpret_cast<const f32x4*>(&o),
                                    reinterpret_cast<f32x4*>(out) + i4);
    }
}

extern "C" void kernel_launch(void* const* d_in, const int* in_sizes, int n_in,
                              void* d_out, int out_size, void* d_ws, size_t ws_size,
                              hipStream_t stream) {
    const float* x  = (const float*)d_in[0];   // [N, C, H, W] f32
    const float* w  = (const float*)d_in[1];   // [C] f32
    const float* mu = (const float*)d_in[2];   // scalar (1-elem array)
    float* out = (float*)d_out;

    float* Spart = (float*)d_ws;                       // 32*64*784*4 = 6.4 MB
    float* S     = Spart + (size_t)NCHUNK * ND * HWD;  // 64*784 = 200 KB

    // Pass 1: 32 chunks x 64 samples, 256 threads (4 waves x 8 channels)
    dim3 g1(NCHUNK, ND);
    pass1_kernel<<<g1, 256, 0, stream>>>(x, w, mu, Spart);

    // Reduce: 50176 outputs
    reduce_kernel<<<ND * HWD / 256, 256, 0, stream>>>(Spart, S);

    // Mult: pure streaming multiply
    mult_kernel<<<3136, 256, 0, stream>>>(x, S, out);
}